// Round 8
// baseline (429.422 us; speedup 1.0000x reference)
//
#include <hip/hip_runtime.h>

typedef _Float16 h8_t __attribute__((ext_vector_type(8)));
typedef _Float16 h4_t __attribute__((ext_vector_type(4)));
typedef float f4_t __attribute__((ext_vector_type(4)));

#define NTOK 9216
#define CMID 128
#define NBATCH 2
#define KCHUNK 5                  // 720 blocks: all resident at 3 blocks/CU
#define NKT 144                   // 64-key tiles per batch
#define NSTAT 18432.0f            // 2*9216 elements per channel for BN stats

// MFMA fragment recipe (verified R2-R11):
//   A-frag: lane(l16,quad) holds A[m=l16][k=quad*8+j]   (h8 from [m][k] row)
//   B-frag: lane(l16,quad) holds B[n=l16][k=quad*8+j]   (h8 from [n][k] row)
//   D:      lane(l16,quad) holds D[row=quad*4+r][col=l16]
// R8 lesson: W frags must be LDS-staged (in-loop per-lane global loads = L2
//   latency on critical path).
// R6/R10/R11 lesson: unified VGPR+AGPR budget; extra live registers OR
//   complex per-element addressing tips the allocator into scratch.
// R12 lesson (measured): __launch_bounds__(256,4) caps regs at 64+64 ->
//   spill (FETCH 42->647 MB). Never tighten below (256,3).
// R13 lesson (measured): swapped QK^T + packed P-store = 186->176 us;
//   SQ_LDS_BANK_CONFLICT ~1.4e7 is STRUCTURAL (wave64 b128 = 8 dword/bank
//   minimum counted). Banks are NOT a lever.
// R14 lesson (measured): reg-prefetch of K/V across barriers -> scratch
//   spill (WRITE 54->640 MB). Reg-staging does not fit the envelope.
// R15 lesson (measured): residency ceiling is 3 blocks/CU from UNIFIED regs:
//   84 VGPR + 64 AGPR (O accums) = 148/wave; 4 waves/SIMD x148 = 592 > 512
//   pool. Grids > 768 blocks run as two dispatch rounds (176->223 us).
//   KCHUNK=5 (720 blocks) is the best fill.
// R16/R17 lesson (measured): global_load_lds staging into the barrier-
//   multiplexed UBuf (K-tile | Pl union) passes first correctness but
//   diverges post-timing under graph replay (absmax 2.1) -- an intermittent
//   race. Abandoned per pre-commitment.
// R18 (measured): R13-exact re-anchor verified: 331.7 us total, flash
//   173-176 us, all counters match Round 2. R16/17 was the kernel, not env.
// R19 (this round): delete barrier B3 by un-aliasing Pl from Kl. B3 only
//   guarded the Kl->Pl WAR; P rows are WAVE-PRIVATE (wave w writes and
//   reads exactly rows [w*32, w*32+32)), intra-wave store->read ordering
//   is lgkmcnt (compiler-inserted; current code already relies on it).
//   Separate Pl[128][72] -> 2 barriers/tile instead of 3; waves desync
//   across exp/PV phase -> cross-phase pipe overlap (QK^T MFMA || exp VALU
//   || PV MFMA across waves). LDS 36864 -> 54272 B; x3 = 162816 <= 163840
//   so 3 blocks/CU residency holds (gate: occupancy must stay ~28%).
//   Pitch stays 72: 144 B rows keep ds_read_b128 16B-aligned (pitch 68
//   would put odd rows at 8 mod 16 -> illegal b128 alignment).

__device__ __forceinline__ h8_t cvt_f32x8_h8(const float* p) {
  f4_t a = *(const f4_t*)p, b = *(const f4_t*)(p + 4);
  h8_t h;
#pragma unroll
  for (int u = 0; u < 4; u++) { h[u] = (_Float16)a[u]; h[u + 4] = (_Float16)b[u]; }
  return h;
}

// ---------------------------------------------------------------------------
// Kernel A: QKV projection via MFMA (FROZEN from R9/R13).
// ---------------------------------------------------------------------------
__global__ __launch_bounds__(256) void qkv_kernel(
    const float* __restrict__ x, const float* __restrict__ Wk,
    const float* __restrict__ Wv, const float* __restrict__ Wq,
    _Float16* __restrict__ Qt, _Float16* __restrict__ Kt,
    _Float16* __restrict__ V)
{
  const int b  = blockIdx.z;
  const int n0 = blockIdx.x * 64;
  const int o0 = blockIdx.y * 64;
  const int tid = threadIdx.x;
  const int wave = tid >> 6, lane = tid & 63, quad = lane >> 4, l16 = lane & 15;

  __shared__ _Float16 Wl[64][136];   // A tile [o][c-chunk]
  __shared__ _Float16 xl[64][136];   // B tile [n][c-chunk]; reused as V staging
  __shared__ _Float16 Tt[128][68];   // transpose staging (f16)

  const float* Wsel; int orow;
  if (o0 < 128)      { Wsel = Wq; orow = o0; }
  else if (o0 < 256) { Wsel = Wk; orow = o0 - 128; }
  else               { Wsel = Wv; orow = o0 - 256; }

  f4_t acc[4];
#pragma unroll
  for (int t = 0; t < 4; t++) acc[t] = (f4_t)(0.f);

  for (int kc = 0; kc < 256; kc += 128) {
    __syncthreads();
#pragma unroll
    for (int it = 0; it < 4; it++) {
      int idx = tid + it * 256;
      int row = idx >> 4, oc = idx & 15;
      *(h8_t*)&Wl[row][oc * 8] =
          cvt_f32x8_h8(&Wsel[(size_t)(orow + row) * 256 + kc + oc * 8]);
    }
#pragma unroll
    for (int it = 0; it < 8; it++) {
      int idx = tid + it * 256;
      int cl = idx >> 4, u = idx & 15;
      f4_t v = *(const f4_t*)&x[(size_t)(b * 256 + kc + cl) * NTOK + n0 + u * 4];
      h4_t h;
#pragma unroll
      for (int j = 0; j < 4; j++) h[j] = (_Float16)v[j];
      *(h4_t*)&Tt[cl][u * 4] = h;
    }
    __syncthreads();
#pragma unroll
    for (int it = 0; it < 4; it++) {
      int idx = tid + it * 256;
      int nl = idx & 63, oc = idx >> 6;   // oc 0..15
      h8_t h;
#pragma unroll
      for (int j = 0; j < 8; j++) h[j] = Tt[oc * 8 + j][nl];
      *(h8_t*)&xl[nl][oc * 8] = h;
    }
    __syncthreads();
#pragma unroll
    for (int ko = 0; ko < 4; ko++) {
      h8_t af = *(const h8_t*)&Wl[wave * 16 + l16][ko * 32 + quad * 8];
#pragma unroll
      for (int t = 0; t < 4; t++) {
        h8_t bf = *(const h8_t*)&xl[t * 16 + l16][ko * 32 + quad * 8];
        acc[t] = __builtin_amdgcn_mfma_f32_16x16x32_f16(af, bf, acc[t], 0, 0, 0);
      }
    }
  }

  const float qscale = 0.08838834764831845f * 1.4426950408889634f; // 128^-0.5*log2e
  if (o0 < 256) {
    _Float16* dst = (o0 < 128) ? Qt : Kt;
    const int od = ((o0 < 128) ? o0 : (o0 - 128)) + wave * 16 + quad * 4;
    const float s = (o0 < 128) ? qscale : 1.0f;
#pragma unroll
    for (int t = 0; t < 4; t++) {
      int n = n0 + t * 16 + l16;
      h4_t h;
#pragma unroll
      for (int r = 0; r < 4; r++) h[r] = (_Float16)(acc[t][r] * s);
      *(h4_t*)&dst[(size_t)(b * NTOK + n) * CMID + od] = h;
    }
  } else {
    // V branch: transpose acc through xl (dead after MFMA) -> coalesced h8
    __syncthreads();   // all waves done reading xl
    const int cl0 = wave * 16 + quad * 4;   // local channel row base
#pragma unroll
    for (int t = 0; t < 4; t++)
#pragma unroll
      for (int r = 0; r < 4; r++)
        xl[cl0 + r][t * 16 + l16] = (_Float16)acc[t][r];   // [c][n], pitch 136
    __syncthreads();
    const int c0 = o0 - 256;
#pragma unroll
    for (int it = 0; it < 2; it++) {
      int idx = tid + it * 256;
      int row = idx >> 3, ch = idx & 7;     // row: 64 channels, ch: 8 h8-chunks
      *(h8_t*)&V[(size_t)(b * CMID + c0 + row) * NTOK + n0 + ch * 8] =
          *(const h8_t*)&xl[row][ch * 8];
    }
  }
}

// ---------------------------------------------------------------------------
// Kernel B: split-K flash. R19: Pl un-aliased from Kl -> B3 deleted
// (2 barriers/tile). P rows are wave-private; intra-wave lgkmcnt orders
// store->read. LDS 54272 B, 3 blocks/CU preserved.
// ---------------------------------------------------------------------------
__global__ __launch_bounds__(256, 3) void flash_kernel(
    const _Float16* __restrict__ Qt, const _Float16* __restrict__ Kt,
    const _Float16* __restrict__ V,
    float* __restrict__ gcn_acc, float* __restrict__ l_acc)
{
  const int b  = blockIdx.z;
  const int kc = blockIdx.y;
  const int q0 = blockIdx.x * 128;
  const int tid = threadIdx.x;
  const int wave = tid >> 6, lane = tid & 63, quad = lane >> 4, l16 = lane & 15;

  __shared__ _Float16 Vl[128][72];             // [c][key]
  __shared__ _Float16 Kl[64][136];             // [key][c]
  __shared__ _Float16 Pl[128][72];             // [query][key] — wave-private rows

  h8_t qf[2][4];
#pragma unroll
  for (int qi = 0; qi < 2; qi++) {
    const _Float16* qp =
        Qt + (size_t)(b * NTOK + q0 + wave * 32 + qi * 16 + l16) * CMID;
#pragma unroll
    for (int ch = 0; ch < 4; ch++)
      qf[qi][ch] = *(const h8_t*)(qp + ch * 32 + quad * 8);
  }

  f4_t O[2][8];
#pragma unroll
  for (int qi = 0; qi < 2; qi++)
#pragma unroll
    for (int t = 0; t < 8; t++) O[qi][t] = (f4_t)(0.f);
  float l_r[2] = {0.f, 0.f};

  const int t0 = (kc * NKT) / KCHUNK;
  const int t1 = ((kc + 1) * NKT) / KCHUNK;
  for (int k0 = t0 * 64; k0 < t1 * 64; k0 += 64) {
    __syncthreads();   // B1: prior iter's Kl/Vl reads complete
    {
      const h8_t* src = (const h8_t*)(Kt + (size_t)(b * NTOK + k0) * CMID);
#pragma unroll
      for (int r = 0; r < 4; r++) {
        int idx = tid + r * 256;
        int row = idx >> 4, ch = idx & 15;
        *(h8_t*)&Kl[row][ch * 8] = src[idx];
      }
      const _Float16* vs = V + (size_t)(b * CMID) * NTOK + k0;
#pragma unroll
      for (int r = 0; r < 4; r++) {
        int idx = tid + r * 256;
        int row = idx >> 3, ch = idx & 7;
        *(h8_t*)&Vl[row][ch * 8] = *(const h8_t*)(vs + (size_t)row * NTOK + ch * 8);
      }
    }
    __syncthreads();   // B2: tiles staged

    // Swapped QK^T: A=kf, B=qf  ->  S[qi][t][r] is
    //   query = q0 + wave*32 + qi*16 + l16   (lane-fixed)
    //   key   = k0 + t*16 + quad*4 + r       (4 consecutive keys per lane)
    f4_t S[2][4];
#pragma unroll
    for (int qi = 0; qi < 2; qi++)
#pragma unroll
      for (int t = 0; t < 4; t++) S[qi][t] = (f4_t)(0.f);
#pragma unroll
    for (int ch = 0; ch < 4; ch++)
#pragma unroll
      for (int t = 0; t < 4; t++) {
        h8_t kf = *(const h8_t*)&Kl[t * 16 + l16][ch * 32 + quad * 8];
        S[0][t] = __builtin_amdgcn_mfma_f32_16x16x32_f16(kf, qf[0][ch], S[0][t], 0, 0, 0);
        S[1][t] = __builtin_amdgcn_mfma_f32_16x16x32_f16(kf, qf[1][ch], S[1][t], 0, 0, 0);
      }
    // NO B3: Pl is a separate buffer; wave w writes/reads only rows
    // [w*32, w*32+32). lgkmcnt (compiler) orders intra-wave store->read.

    // P-store: 4 consecutive keys -> one packed h4 (ds_write_b64, bank-minimal:
    // start bank = (4*l16 + 2*quad) mod 32 -> exactly 4 dword-accesses/bank).
#pragma unroll
    for (int qi = 0; qi < 2; qi++)
#pragma unroll
      for (int t = 0; t < 4; t++) {
        h4_t h;
#pragma unroll
        for (int r = 0; r < 4; r++) {
          float p = exp2f(S[qi][t][r] - 8.0f);
          l_r[qi] += p;
          h[r] = (_Float16)p;
        }
        *(h4_t*)&Pl[wave * 32 + qi * 16 + l16][t * 16 + quad * 4] = h;
      }

#pragma unroll
    for (int ch = 0; ch < 2; ch++) {
      h8_t pf0 = *(const h8_t*)&Pl[wave * 32 + l16][ch * 32 + quad * 8];
      h8_t pf1 = *(const h8_t*)&Pl[wave * 32 + 16 + l16][ch * 32 + quad * 8];
#pragma unroll
      for (int t = 0; t < 8; t++) {
        h8_t vf = *(const h8_t*)&Vl[t * 16 + l16][ch * 32 + quad * 8];
        O[0][t] = __builtin_amdgcn_mfma_f32_16x16x32_f16(pf0, vf, O[0][t], 0, 0, 0);
        O[1][t] = __builtin_amdgcn_mfma_f32_16x16x32_f16(pf1, vf, O[1][t], 0, 0, 0);
      }
    }
  }

  // l-reduce: lane's partial covers keys {t*16+quad*4+r}; sum across quads
  // (lane bits 4,5), then one atomic per query from quad 0.
#pragma unroll
  for (int qi = 0; qi < 2; qi++) {
    float v = l_r[qi];
    v += __shfl_xor(v, 16);
    v += __shfl_xor(v, 32);
    if (quad == 0)
      atomicAdd(&l_acc[b * NTOK + q0 + wave * 32 + qi * 16 + l16], v);
  }
#pragma unroll
  for (int qi = 0; qi < 2; qi++)
#pragma unroll
    for (int t = 0; t < 8; t++)
#pragma unroll
      for (int r = 0; r < 4; r++)
        atomicAdd(&gcn_acc[(size_t)(b * NTOK + q0 + wave * 32 + qi * 16 + quad * 4 + r)
                               * CMID + t * 16 + l16],
                  O[qi][t][r]);
}

// ---------------------------------------------------------------------------
// Kernel C: conv1 via MFMA (FROZEN from R9).
// ---------------------------------------------------------------------------
__global__ __launch_bounds__(256) void conv1_kernel(
    const float* __restrict__ gcn_acc, const float* __restrict__ l_acc,
    const float* __restrict__ Wc1,
    _Float16* __restrict__ g1t, float* __restrict__ sum1, float* __restrict__ sq1)
{
  const int b  = blockIdx.z;
  const int n0 = blockIdx.x * 64;
  const int o0 = blockIdx.y * 64;
  const int tid = threadIdx.x;
  const int wave = tid >> 6, lane = tid & 63, quad = lane >> 4, l16 = lane & 15;

  __shared__ _Float16 Gl[64][136];   // [n][c]
  __shared__ _Float16 Wcl[64][136];  // [o][c]
  __shared__ float rl[64];
  __shared__ float ssum[64], ssq[64];

  if (tid < 64) {
    rl[tid] = 1.0f / l_acc[b * NTOK + n0 + tid];
    ssum[tid] = 0.f; ssq[tid] = 0.f;
  }
  __syncthreads();

#pragma unroll
  for (int it = 0; it < 4; it++) {
    int idx = tid + it * 256;
    int n = idx >> 4, oc = idx & 15;
    const float* gp = &gcn_acc[(size_t)(b * NTOK + n0 + n) * CMID + oc * 8];
    float s = rl[n];
    f4_t a = *(const f4_t*)gp, c = *(const f4_t*)(gp + 4);
    h8_t h;
#pragma unroll
    for (int u = 0; u < 4; u++) {
      h[u] = (_Float16)(a[u] * s);
      h[u + 4] = (_Float16)(c[u] * s);
    }
    *(h8_t*)&Gl[n][oc * 8] = h;
  }
#pragma unroll
  for (int it = 0; it < 4; it++) {
    int idx = tid + it * 256;
    int row = idx >> 4, oc = idx & 15;
    *(h8_t*)&Wcl[row][oc * 8] =
        cvt_f32x8_h8(&Wc1[(size_t)(o0 + row) * 128 + oc * 8]);
  }
  __syncthreads();

  f4_t acc[4];
#pragma unroll
  for (int t = 0; t < 4; t++) acc[t] = (f4_t)(0.f);
#pragma unroll
  for (int ko = 0; ko < 4; ko++) {
    h8_t af = *(const h8_t*)&Gl[wave * 16 + l16][ko * 32 + quad * 8];
#pragma unroll
    for (int t = 0; t < 4; t++) {
      h8_t bf = *(const h8_t*)&Wcl[t * 16 + l16][ko * 32 + quad * 8];
      acc[t] = __builtin_amdgcn_mfma_f32_16x16x32_f16(af, bf, acc[t], 0, 0, 0);
    }
  }

  // D: row = n (wave*16+quad*4+r), col = o (t*16+l16)
#pragma unroll
  for (int t = 0; t < 4; t++) {
    int ol = t * 16 + l16;
    float ls = 0.f, lq = 0.f;
#pragma unroll
    for (int r = 0; r < 4; r++) {
      float v = acc[t][r];
      ls += v; lq += v * v;
      g1t[(size_t)(b * NTOK + n0 + wave * 16 + quad * 4 + r) * 256 + o0 + ol] =
          (_Float16)v;
    }
    atomicAdd(&ssum[ol], ls);
    atomicAdd(&ssq[ol], lq);
  }
  __syncthreads();
  if (tid < 64) {
    atomicAdd(&sum1[o0 + tid], ssum[tid]);
    atomicAdd(&sq1[o0 + tid], ssq[tid]);
  }
}

// ---------------------------------------------------------------------------
// Kernel E: out2 via MFMA (FROZEN from R9).
// ---------------------------------------------------------------------------
__global__ __launch_bounds__(256) void out_kernel(
    const float* __restrict__ x, const _Float16* __restrict__ g1t,
    const float* __restrict__ Wout,
    const float* __restrict__ sum1, const float* __restrict__ sq1,
    const float* __restrict__ gamma1, const float* __restrict__ beta1,
    _Float16* __restrict__ out2, float* __restrict__ sum2, float* __restrict__ sq2)
{
  const int b  = blockIdx.z;
  const int n0 = blockIdx.x * 64;
  const int o0 = blockIdx.y * 64;
  const int tid = threadIdx.x;
  const int wave = tid >> 6, lane = tid & 63, quad = lane >> 4, l16 = lane & 15;

  __shared__ _Float16 Wol[64][136];  // A tile [o][k-chunk]
  __shared__ _Float16 Bl[64][136];   // B tile [n][k-chunk]
  __shared__ _Float16 Tt[128][68];   // transpose staging (f16)
  __shared__ _Float16 scs[256], shs[256];
  __shared__ float ssum[64], ssq[64];

  {  // BN1 params inline
    float m = sum1[tid] * (1.f / NSTAT);
    float var = sq1[tid] * (1.f / NSTAT) - m * m;
    float s = gamma1[tid] * rsqrtf(var + 1e-5f);
    scs[tid] = (_Float16)s;
    shs[tid] = (_Float16)(beta1[tid] - m * s);
  }
  if (tid < 64) { ssum[tid] = 0.f; ssq[tid] = 0.f; }

  f4_t acc[4];
#pragma unroll
  for (int t = 0; t < 4; t++) acc[t] = (f4_t)(0.f);

  for (int kc = 0; kc < 512; kc += 128) {
    __syncthreads();
#pragma unroll
    for (int it = 0; it < 4; it++) {
      int idx = tid + it * 256;
      int row = idx >> 4, oc = idx & 15;
      *(h8_t*)&Wol[row][oc * 8] =
          cvt_f32x8_h8(&Wout[(size_t)(o0 + row) * 512 + kc + oc * 8]);
    }
    if (kc < 256) {
#pragma unroll
      for (int it = 0; it < 8; it++) {
        int idx = tid + it * 256;
        int cl = idx >> 4, u = idx & 15;
        f4_t v = *(const f4_t*)&x[(size_t)(b * 256 + kc + cl) * NTOK + n0 + u * 4];
        h4_t h;
#pragma unroll
        for (int j = 0; j < 4; j++) h[j] = (_Float16)v[j];
        *(h4_t*)&Tt[cl][u * 4] = h;
      }
      __syncthreads();
#pragma unroll
      for (int it = 0; it < 4; it++) {
        int idx = tid + it * 256;
        int nl = idx & 63, oc = idx >> 6;
        h8_t h;
#pragma unroll
        for (int j = 0; j < 8; j++) h[j] = Tt[oc * 8 + j][nl];
        *(h8_t*)&Bl[nl][oc * 8] = h;
      }
    } else {
#pragma unroll
      for (int it = 0; it < 4; it++) {
        int idx = tid + it * 256;
        int n = idx >> 4, oc = idx & 15;
        int cg = kc - 256 + oc * 8;
        h8_t g = *(const h8_t*)&g1t[(size_t)(b * NTOK + n0 + n) * 256 + cg];
        h8_t h;
#pragma unroll
        for (int u = 0; u < 8; u++) {
          float t = (float)scs[cg + u] * (float)g[u] + (float)shs[cg + u];
          h[u] = (_Float16)(t > 0.f ? t : 0.f);
        }
        *(h8_t*)&Bl[n][oc * 8] = h;
      }
    }
    __syncthreads();
#pragma unroll
    for (int ko = 0; ko < 4; ko++) {
      h8_t af = *(const h8_t*)&Wol[wave * 16 + l16][ko * 32 + quad * 8];
#pragma unroll
      for (int t = 0; t < 4; t++) {
        h8_t bf = *(const h8_t*)&Bl[t * 16 + l16][ko * 32 + quad * 8];
        acc[t] = __builtin_amdgcn_mfma_f32_16x16x32_f16(af, bf, acc[t], 0, 0, 0);
      }
    }
  }

#pragma unroll
  for (int r = 0; r < 4; r++) {
    int o = o0 + wave * 16 + quad * 4 + r;
    float ls = 0.f, lq = 0.f;
#pragma unroll
    for (int t = 0; t < 4; t++) {
      float v = acc[t][r];
      ls += v; lq += v * v;
      out2[(size_t)(b * 256 + o) * NTOK + n0 + t * 16 + l16] = (_Float16)v;
    }
    atomicAdd(&ssum[wave * 16 + quad * 4 + r], ls);
    atomicAdd(&ssq[wave * 16 + quad * 4 + r], lq);
  }
  __syncthreads();
  if (tid < 64) {
    atomicAdd(&sum2[o0 + tid], ssum[tid]);
    atomicAdd(&sq2[o0 + tid], ssq[tid]);
  }
}

// ---------------------------------------------------------------------------
// Kernel G: out = relu(sc2*out2 + sh2); BN2 params inline (FROZEN from R9).
// ---------------------------------------------------------------------------
__global__ __launch_bounds__(256) void bn2_kernel(
    const _Float16* __restrict__ out2, const float* __restrict__ sum2,
    const float* __restrict__ sq2, const float* __restrict__ gamma2,
    const float* __restrict__ beta2, float* __restrict__ out)
{
  size_t i = ((size_t)blockIdx.x * 256 + threadIdx.x) * 8;
  int o = (int)((i / NTOK) & 255);
  float m = sum2[o] * (1.f / NSTAT);
  float var = sq2[o] * (1.f / NSTAT) - m * m;
  float s = gamma2[o] * rsqrtf(var + 1e-5f);
  float h = beta2[o] - m * s;
  h8_t v = *(const h8_t*)&out2[i];
  f4_t r0, r1;
#pragma unroll
  for (int u = 0; u < 4; u++) {
    float t0 = s * (float)v[u] + h;
    float t1 = s * (float)v[u + 4] + h;
    r0[u] = t0 > 0.f ? t0 : 0.f;
    r1[u] = t1 > 0.f ? t1 : 0.f;
  }
  *(f4_t*)&out[i] = r0;
  *(f4_t*)&out[i + 4] = r1;
}

// ---------------------------------------------------------------------------
// ws (18.89 MB, known-safe): [0,8K) stats; base: R0..R3 (4.72 MB each):
//   Qt(R0) Kt(R1) V(R2); g1t[n][256] aliases R0+R1 (dead after flash);
//   out2[o][n] aliases R2+R3.  d_out = flash scratch (gcn_acc+l_acc).
// ---------------------------------------------------------------------------
extern "C" void kernel_launch(void* const* d_in, const int* in_sizes, int n_in,
                              void* d_out, int out_size, void* d_ws, size_t ws_size,
                              hipStream_t stream) {
  const float* x      = (const float*)d_in[0];
  const float* Wk     = (const float*)d_in[1];
  const float* Wv     = (const float*)d_in[2];
  const float* Wq     = (const float*)d_in[3];
  const float* Wc1    = (const float*)d_in[4];
  const float* gamma1 = (const float*)d_in[5];
  const float* beta1  = (const float*)d_in[6];
  const float* Wout   = (const float*)d_in[7];
  const float* gamma2 = (const float*)d_in[8];
  const float* beta2  = (const float*)d_in[9];
  float* out = (float*)d_out;

  char* ws = (char*)d_ws;
  float* sum1 = (float*)(ws + 0 * 1024);
  float* sq1  = (float*)(ws + 1 * 1024);
  float* sum2 = (float*)(ws + 2 * 1024);
  float* sq2  = (float*)(ws + 3 * 1024);

  const size_t R = (size_t)NBATCH * NTOK * CMID * 2;  // 4,718,592 B per region
  char* base = ws + 8 * 1024;
  _Float16* Qt   = (_Float16*)(base + 0 * R);
  _Float16* Kt   = (_Float16*)(base + 1 * R);
  _Float16* V    = (_Float16*)(base + 2 * R);
  _Float16* g1t  = (_Float16*)(base + 0 * R);  // [b][n][256], aliases Qt+Kt
  _Float16* out2 = (_Float16*)(base + 2 * R);  // [b][o][n],   aliases V+spare

  float* gcn_acc = (float*)d_out;                              // 9,437,184 B
  float* l_acc   = (float*)((char*)d_out + (size_t)NBATCH * NTOK * CMID * 4);

  hipMemsetAsync(sum1, 0, 4 * 1024, stream);
  hipMemsetAsync(gcn_acc, 0,
                 (size_t)NBATCH * NTOK * CMID * 4 + (size_t)NBATCH * NTOK * 4,
                 stream);

  qkv_kernel<<<dim3(144, 6, 2), 256, 0, stream>>>(x, Wk, Wv, Wq, Qt, Kt, V);
  flash_kernel<<<dim3(72, KCHUNK, 2), 256, 0, stream>>>(Qt, Kt, V, gcn_acc, l_acc);
  conv1_kernel<<<dim3(144, 4, 2), 256, 0, stream>>>(gcn_acc, l_acc, Wc1, g1t, sum1, sq1);
  out_kernel<<<dim3(144, 4, 2), 256, 0, stream>>>(x, g1t, Wout, sum1, sq1, gamma1, beta1,
                                                  out2, sum2, sq2);
  bn2_kernel<<<2304, 256, 0, stream>>>(out2, sum2, sq2, gamma2, beta2, out);
}

// Round 9
// 313.800 us; speedup vs baseline: 1.3685x; 1.3685x over previous
//
#include <hip/hip_runtime.h>

typedef _Float16 h8_t __attribute__((ext_vector_type(8)));
typedef _Float16 h4_t __attribute__((ext_vector_type(4)));
typedef float f4_t __attribute__((ext_vector_type(4)));

#define NTOK 9216
#define CMID 128
#define NBATCH 2
#define KCHUNK 5                  // 720 blocks: all resident at 3 blocks/CU
#define NKT 144                   // 64-key tiles per batch
#define NSTAT 18432.0f            // 2*9216 elements per channel for BN stats

// MFMA fragment recipe (verified R2-R11):
//   A-frag: lane(l16,quad) holds A[m=l16][k=quad*8+j]   (h8 from [m][k] row)
//   B-frag: lane(l16,quad) holds B[n=l16][k=quad*8+j]   (h8 from [n][k] row)
//   D:      lane(l16,quad) holds D[row=quad*4+r][col=l16]
// R8 lesson: W frags must be LDS-staged (in-loop per-lane global loads = L2
//   latency on critical path).
// R6/R10/R11 lesson: unified VGPR+AGPR budget; extra live registers OR
//   complex per-element addressing tips the allocator into scratch.
// R12 lesson (measured): __launch_bounds__(256,4) caps regs at 64+64 ->
//   spill (FETCH 42->647 MB). Never tighten below (256,3).
// R13 lesson (measured): swapped QK^T + packed P-store = 186->176 us;
//   SQ_LDS_BANK_CONFLICT ~1.4e7 is STRUCTURAL (wave64 b128 = 8 dword/bank
//   minimum counted). Banks are NOT a lever.
// R14 lesson (measured): reg-prefetch of K/V across barriers -> scratch
//   spill (WRITE 54->640 MB). Reg-staging does not fit the envelope.
// R15 lesson (measured): residency ceiling is 3 blocks/CU from UNIFIED regs:
//   84 VGPR + 64 AGPR (O accums) = 148/wave; 4 waves/SIMD x148 = 592 > 512
//   pool. Grids > 768 blocks run as two dispatch rounds (176->223 us).
//   KCHUNK=5 (720 blocks) is the best fill.
// R16/R17 lesson (measured): global_load_lds staging into the barrier-
//   multiplexed UBuf passes first correctness but diverges post-timing
//   under graph replay (absmax 2.1) -- intermittent race. Abandoned.
// R18 (measured): R13-exact re-anchor verified: 331.7 us total, flash
//   173-176 us, all counters match Round 2.
// R19 lesson (measured): separate Pl (LDS 36864->54272 B) -> hardware
//   granted only 2 blocks/CU despite 54272*3 <= 163840 (LDS allocation
//   granularity rounds up). Occupancy 28.5->16.7%, flash 270 us. The
//   3-block LDS budget is empirically <= ~37 KB/block, NOT 54.6 KB.
//   Any flash change that grows LDS risks the residency cliff.
// R20 (this round): T5 s_setprio(1) around the QK^T and PV MFMA clusters.
//   Zero LDS / zero register cost. Mechanism: 3 independent blocks/CU sit
//   at different phases (stage/exp-VALU/MFMA); boosting waves inside MFMA
//   bursts wins issue arbitration vs staging waves (attn precedent m191:
//   +4-7%; GEMM-lockstep null m190 -- flash matches the attn case).
//   Gate: all R18 counters must hold exactly; regression >5 us -> strip.

__device__ __forceinline__ h8_t cvt_f32x8_h8(const float* p) {
  f4_t a = *(const f4_t*)p, b = *(const f4_t*)(p + 4);
  h8_t h;
#pragma unroll
  for (int u = 0; u < 4; u++) { h[u] = (_Float16)a[u]; h[u + 4] = (_Float16)b[u]; }
  return h;
}

// ---------------------------------------------------------------------------
// Kernel A: QKV projection via MFMA (FROZEN from R9/R13).
// ---------------------------------------------------------------------------
__global__ __launch_bounds__(256) void qkv_kernel(
    const float* __restrict__ x, const float* __restrict__ Wk,
    const float* __restrict__ Wv, const float* __restrict__ Wq,
    _Float16* __restrict__ Qt, _Float16* __restrict__ Kt,
    _Float16* __restrict__ V)
{
  const int b  = blockIdx.z;
  const int n0 = blockIdx.x * 64;
  const int o0 = blockIdx.y * 64;
  const int tid = threadIdx.x;
  const int wave = tid >> 6, lane = tid & 63, quad = lane >> 4, l16 = lane & 15;

  __shared__ _Float16 Wl[64][136];   // A tile [o][c-chunk]
  __shared__ _Float16 xl[64][136];   // B tile [n][c-chunk]; reused as V staging
  __shared__ _Float16 Tt[128][68];   // transpose staging (f16)

  const float* Wsel; int orow;
  if (o0 < 128)      { Wsel = Wq; orow = o0; }
  else if (o0 < 256) { Wsel = Wk; orow = o0 - 128; }
  else               { Wsel = Wv; orow = o0 - 256; }

  f4_t acc[4];
#pragma unroll
  for (int t = 0; t < 4; t++) acc[t] = (f4_t)(0.f);

  for (int kc = 0; kc < 256; kc += 128) {
    __syncthreads();
#pragma unroll
    for (int it = 0; it < 4; it++) {
      int idx = tid + it * 256;
      int row = idx >> 4, oc = idx & 15;
      *(h8_t*)&Wl[row][oc * 8] =
          cvt_f32x8_h8(&Wsel[(size_t)(orow + row) * 256 + kc + oc * 8]);
    }
#pragma unroll
    for (int it = 0; it < 8; it++) {
      int idx = tid + it * 256;
      int cl = idx >> 4, u = idx & 15;
      f4_t v = *(const f4_t*)&x[(size_t)(b * 256 + kc + cl) * NTOK + n0 + u * 4];
      h4_t h;
#pragma unroll
      for (int j = 0; j < 4; j++) h[j] = (_Float16)v[j];
      *(h4_t*)&Tt[cl][u * 4] = h;
    }
    __syncthreads();
#pragma unroll
    for (int it = 0; it < 4; it++) {
      int idx = tid + it * 256;
      int nl = idx & 63, oc = idx >> 6;   // oc 0..15
      h8_t h;
#pragma unroll
      for (int j = 0; j < 8; j++) h[j] = Tt[oc * 8 + j][nl];
      *(h8_t*)&xl[nl][oc * 8] = h;
    }
    __syncthreads();
#pragma unroll
    for (int ko = 0; ko < 4; ko++) {
      h8_t af = *(const h8_t*)&Wl[wave * 16 + l16][ko * 32 + quad * 8];
#pragma unroll
      for (int t = 0; t < 4; t++) {
        h8_t bf = *(const h8_t*)&xl[t * 16 + l16][ko * 32 + quad * 8];
        acc[t] = __builtin_amdgcn_mfma_f32_16x16x32_f16(af, bf, acc[t], 0, 0, 0);
      }
    }
  }

  const float qscale = 0.08838834764831845f * 1.4426950408889634f; // 128^-0.5*log2e
  if (o0 < 256) {
    _Float16* dst = (o0 < 128) ? Qt : Kt;
    const int od = ((o0 < 128) ? o0 : (o0 - 128)) + wave * 16 + quad * 4;
    const float s = (o0 < 128) ? qscale : 1.0f;
#pragma unroll
    for (int t = 0; t < 4; t++) {
      int n = n0 + t * 16 + l16;
      h4_t h;
#pragma unroll
      for (int r = 0; r < 4; r++) h[r] = (_Float16)(acc[t][r] * s);
      *(h4_t*)&dst[(size_t)(b * NTOK + n) * CMID + od] = h;
    }
  } else {
    // V branch: transpose acc through xl (dead after MFMA) -> coalesced h8
    __syncthreads();   // all waves done reading xl
    const int cl0 = wave * 16 + quad * 4;   // local channel row base
#pragma unroll
    for (int t = 0; t < 4; t++)
#pragma unroll
      for (int r = 0; r < 4; r++)
        xl[cl0 + r][t * 16 + l16] = (_Float16)acc[t][r];   // [c][n], pitch 136
    __syncthreads();
    const int c0 = o0 - 256;
#pragma unroll
    for (int it = 0; it < 2; it++) {
      int idx = tid + it * 256;
      int row = idx >> 3, ch = idx & 7;     // row: 64 channels, ch: 8 h8-chunks
      *(h8_t*)&V[(size_t)(b * CMID + c0 + row) * NTOK + n0 + ch * 8] =
          *(const h8_t*)&xl[row][ch * 8];
    }
  }
}

// ---------------------------------------------------------------------------
// Kernel B: split-K flash (R13-exact memory layout + R20 setprio around
// MFMA clusters).
// ---------------------------------------------------------------------------
__global__ __launch_bounds__(256, 3) void flash_kernel(
    const _Float16* __restrict__ Qt, const _Float16* __restrict__ Kt,
    const _Float16* __restrict__ V,
    float* __restrict__ gcn_acc, float* __restrict__ l_acc)
{
  const int b  = blockIdx.z;
  const int kc = blockIdx.y;
  const int q0 = blockIdx.x * 128;
  const int tid = threadIdx.x;
  const int wave = tid >> 6, lane = tid & 63, quad = lane >> 4, l16 = lane & 15;

  __shared__ _Float16 Vl[128][72];             // [c][key]
  __shared__ alignas(16) _Float16 UBuf[9216];  // union: Kl[64][136] | Pl[128][72]
#define KL(r, c) UBuf[(r) * 136 + (c)]
#define PL(r, c) UBuf[(r) * 72 + (c)]

  h8_t qf[2][4];
#pragma unroll
  for (int qi = 0; qi < 2; qi++) {
    const _Float16* qp =
        Qt + (size_t)(b * NTOK + q0 + wave * 32 + qi * 16 + l16) * CMID;
#pragma unroll
    for (int ch = 0; ch < 4; ch++)
      qf[qi][ch] = *(const h8_t*)(qp + ch * 32 + quad * 8);
  }

  f4_t O[2][8];
#pragma unroll
  for (int qi = 0; qi < 2; qi++)
#pragma unroll
    for (int t = 0; t < 8; t++) O[qi][t] = (f4_t)(0.f);
  float l_r[2] = {0.f, 0.f};

  const int t0 = (kc * NKT) / KCHUNK;
  const int t1 = ((kc + 1) * NKT) / KCHUNK;
  for (int k0 = t0 * 64; k0 < t1 * 64; k0 += 64) {
    __syncthreads();   // B1: prior iter's Pl/Vl reads complete
    {
      const h8_t* src = (const h8_t*)(Kt + (size_t)(b * NTOK + k0) * CMID);
#pragma unroll
      for (int r = 0; r < 4; r++) {
        int idx = tid + r * 256;
        int row = idx >> 4, ch = idx & 15;
        *(h8_t*)&KL(row, ch * 8) = src[idx];
      }
      const _Float16* vs = V + (size_t)(b * CMID) * NTOK + k0;
#pragma unroll
      for (int r = 0; r < 4; r++) {
        int idx = tid + r * 256;
        int row = idx >> 3, ch = idx & 7;
        *(h8_t*)&Vl[row][ch * 8] = *(const h8_t*)(vs + (size_t)row * NTOK + ch * 8);
      }
    }
    __syncthreads();   // B2: tiles staged

    // Swapped QK^T: A=kf, B=qf  ->  S[qi][t][r] is
    //   query = q0 + wave*32 + qi*16 + l16   (lane-fixed)
    //   key   = k0 + t*16 + quad*4 + r       (4 consecutive keys per lane)
    f4_t S[2][4];
#pragma unroll
    for (int qi = 0; qi < 2; qi++)
#pragma unroll
      for (int t = 0; t < 4; t++) S[qi][t] = (f4_t)(0.f);
    __builtin_amdgcn_s_setprio(1);   // T5: favor MFMA-phase waves
#pragma unroll
    for (int ch = 0; ch < 4; ch++)
#pragma unroll
      for (int t = 0; t < 4; t++) {
        h8_t kf = *(const h8_t*)&KL(t * 16 + l16, ch * 32 + quad * 8);
        S[0][t] = __builtin_amdgcn_mfma_f32_16x16x32_f16(kf, qf[0][ch], S[0][t], 0, 0, 0);
        S[1][t] = __builtin_amdgcn_mfma_f32_16x16x32_f16(kf, qf[1][ch], S[1][t], 0, 0, 0);
      }
    __builtin_amdgcn_s_setprio(0);
    __syncthreads();   // B3: Kl reads done; region becomes Pl

    // P-store: 4 consecutive keys -> one packed h4 (ds_write_b64, bank-minimal:
    // start bank = (4*l16 + 2*quad) mod 32 -> exactly 4 dword-accesses/bank).
#pragma unroll
    for (int qi = 0; qi < 2; qi++)
#pragma unroll
      for (int t = 0; t < 4; t++) {
        h4_t h;
#pragma unroll
        for (int r = 0; r < 4; r++) {
          float p = exp2f(S[qi][t][r] - 8.0f);
          l_r[qi] += p;
          h[r] = (_Float16)p;
        }
        *(h4_t*)&PL(wave * 32 + qi * 16 + l16, t * 16 + quad * 4) = h;
      }

    __builtin_amdgcn_s_setprio(1);   // T5: PV MFMA cluster
#pragma unroll
    for (int ch = 0; ch < 2; ch++) {
      h8_t pf0 = *(const h8_t*)&PL(wave * 32 + l16, ch * 32 + quad * 8);
      h8_t pf1 = *(const h8_t*)&PL(wave * 32 + 16 + l16, ch * 32 + quad * 8);
#pragma unroll
      for (int t = 0; t < 8; t++) {
        h8_t vf = *(const h8_t*)&Vl[t * 16 + l16][ch * 32 + quad * 8];
        O[0][t] = __builtin_amdgcn_mfma_f32_16x16x32_f16(pf0, vf, O[0][t], 0, 0, 0);
        O[1][t] = __builtin_amdgcn_mfma_f32_16x16x32_f16(pf1, vf, O[1][t], 0, 0, 0);
      }
    }
    __builtin_amdgcn_s_setprio(0);
  }
#undef KL
#undef PL

  // l-reduce: lane's partial covers keys {t*16+quad*4+r}; sum across quads
  // (lane bits 4,5), then one atomic per query from quad 0.
#pragma unroll
  for (int qi = 0; qi < 2; qi++) {
    float v = l_r[qi];
    v += __shfl_xor(v, 16);
    v += __shfl_xor(v, 32);
    if (quad == 0)
      atomicAdd(&l_acc[b * NTOK + q0 + wave * 32 + qi * 16 + l16], v);
  }
#pragma unroll
  for (int qi = 0; qi < 2; qi++)
#pragma unroll
    for (int t = 0; t < 8; t++)
#pragma unroll
      for (int r = 0; r < 4; r++)
        atomicAdd(&gcn_acc[(size_t)(b * NTOK + q0 + wave * 32 + qi * 16 + quad * 4 + r)
                               * CMID + t * 16 + l16],
                  O[qi][t][r]);
}

// ---------------------------------------------------------------------------
// Kernel C: conv1 via MFMA (FROZEN from R9).
// ---------------------------------------------------------------------------
__global__ __launch_bounds__(256) void conv1_kernel(
    const float* __restrict__ gcn_acc, const float* __restrict__ l_acc,
    const float* __restrict__ Wc1,
    _Float16* __restrict__ g1t, float* __restrict__ sum1, float* __restrict__ sq1)
{
  const int b  = blockIdx.z;
  const int n0 = blockIdx.x * 64;
  const int o0 = blockIdx.y * 64;
  const int tid = threadIdx.x;
  const int wave = tid >> 6, lane = tid & 63, quad = lane >> 4, l16 = lane & 15;

  __shared__ _Float16 Gl[64][136];   // [n][c]
  __shared__ _Float16 Wcl[64][136];  // [o][c]
  __shared__ float rl[64];
  __shared__ float ssum[64], ssq[64];

  if (tid < 64) {
    rl[tid] = 1.0f / l_acc[b * NTOK + n0 + tid];
    ssum[tid] = 0.f; ssq[tid] = 0.f;
  }
  __syncthreads();

#pragma unroll
  for (int it = 0; it < 4; it++) {
    int idx = tid + it * 256;
    int n = idx >> 4, oc = idx & 15;
    const float* gp = &gcn_acc[(size_t)(b * NTOK + n0 + n) * CMID + oc * 8];
    float s = rl[n];
    f4_t a = *(const f4_t*)gp, c = *(const f4_t*)(gp + 4);
    h8_t h;
#pragma unroll
    for (int u = 0; u < 4; u++) {
      h[u] = (_Float16)(a[u] * s);
      h[u + 4] = (_Float16)(c[u] * s);
    }
    *(h8_t*)&Gl[n][oc * 8] = h;
  }
#pragma unroll
  for (int it = 0; it < 4; it++) {
    int idx = tid + it * 256;
    int row = idx >> 4, oc = idx & 15;
    *(h8_t*)&Wcl[row][oc * 8] =
        cvt_f32x8_h8(&Wc1[(size_t)(o0 + row) * 128 + oc * 8]);
  }
  __syncthreads();

  f4_t acc[4];
#pragma unroll
  for (int t = 0; t < 4; t++) acc[t] = (f4_t)(0.f);
#pragma unroll
  for (int ko = 0; ko < 4; ko++) {
    h8_t af = *(const h8_t*)&Gl[wave * 16 + l16][ko * 32 + quad * 8];
#pragma unroll
    for (int t = 0; t < 4; t++) {
      h8_t bf = *(const h8_t*)&Wcl[t * 16 + l16][ko * 32 + quad * 8];
      acc[t] = __builtin_amdgcn_mfma_f32_16x16x32_f16(af, bf, acc[t], 0, 0, 0);
    }
  }

  // D: row = n (wave*16+quad*4+r), col = o (t*16+l16)
#pragma unroll
  for (int t = 0; t < 4; t++) {
    int ol = t * 16 + l16;
    float ls = 0.f, lq = 0.f;
#pragma unroll
    for (int r = 0; r < 4; r++) {
      float v = acc[t][r];
      ls += v; lq += v * v;
      g1t[(size_t)(b * NTOK + n0 + wave * 16 + quad * 4 + r) * 256 + o0 + ol] =
          (_Float16)v;
    }
    atomicAdd(&ssum[ol], ls);
    atomicAdd(&ssq[ol], lq);
  }
  __syncthreads();
  if (tid < 64) {
    atomicAdd(&sum1[o0 + tid], ssum[tid]);
    atomicAdd(&sq1[o0 + tid], ssq[tid]);
  }
}

// ---------------------------------------------------------------------------
// Kernel E: out2 via MFMA (FROZEN from R9).
// ---------------------------------------------------------------------------
__global__ __launch_bounds__(256) void out_kernel(
    const float* __restrict__ x, const _Float16* __restrict__ g1t,
    const float* __restrict__ Wout,
    const float* __restrict__ sum1, const float* __restrict__ sq1,
    const float* __restrict__ gamma1, const float* __restrict__ beta1,
    _Float16* __restrict__ out2, float* __restrict__ sum2, float* __restrict__ sq2)
{
  const int b  = blockIdx.z;
  const int n0 = blockIdx.x * 64;
  const int o0 = blockIdx.y * 64;
  const int tid = threadIdx.x;
  const int wave = tid >> 6, lane = tid & 63, quad = lane >> 4, l16 = lane & 15;

  __shared__ _Float16 Wol[64][136];  // A tile [o][k-chunk]
  __shared__ _Float16 Bl[64][136];   // B tile [n][k-chunk]
  __shared__ _Float16 Tt[128][68];   // transpose staging (f16)
  __shared__ _Float16 scs[256], shs[256];
  __shared__ float ssum[64], ssq[64];

  {  // BN1 params inline
    float m = sum1[tid] * (1.f / NSTAT);
    float var = sq1[tid] * (1.f / NSTAT) - m * m;
    float s = gamma1[tid] * rsqrtf(var + 1e-5f);
    scs[tid] = (_Float16)s;
    shs[tid] = (_Float16)(beta1[tid] - m * s);
  }
  if (tid < 64) { ssum[tid] = 0.f; ssq[tid] = 0.f; }

  f4_t acc[4];
#pragma unroll
  for (int t = 0; t < 4; t++) acc[t] = (f4_t)(0.f);

  for (int kc = 0; kc < 512; kc += 128) {
    __syncthreads();
#pragma unroll
    for (int it = 0; it < 4; it++) {
      int idx = tid + it * 256;
      int row = idx >> 4, oc = idx & 15;
      *(h8_t*)&Wol[row][oc * 8] =
          cvt_f32x8_h8(&Wout[(size_t)(o0 + row) * 512 + kc + oc * 8]);
    }
    if (kc < 256) {
#pragma unroll
      for (int it = 0; it < 8; it++) {
        int idx = tid + it * 256;
        int cl = idx >> 4, u = idx & 15;
        f4_t v = *(const f4_t*)&x[(size_t)(b * 256 + kc + cl) * NTOK + n0 + u * 4];
        h4_t h;
#pragma unroll
        for (int j = 0; j < 4; j++) h[j] = (_Float16)v[j];
        *(h4_t*)&Tt[cl][u * 4] = h;
      }
      __syncthreads();
#pragma unroll
      for (int it = 0; it < 4; it++) {
        int idx = tid + it * 256;
        int nl = idx & 63, oc = idx >> 6;
        h8_t h;
#pragma unroll
        for (int j = 0; j < 8; j++) h[j] = Tt[oc * 8 + j][nl];
        *(h8_t*)&Bl[nl][oc * 8] = h;
      }
    } else {
#pragma unroll
      for (int it = 0; it < 4; it++) {
        int idx = tid + it * 256;
        int n = idx >> 4, oc = idx & 15;
        int cg = kc - 256 + oc * 8;
        h8_t g = *(const h8_t*)&g1t[(size_t)(b * NTOK + n0 + n) * 256 + cg];
        h8_t h;
#pragma unroll
        for (int u = 0; u < 8; u++) {
          float t = (float)scs[cg + u] * (float)g[u] + (float)shs[cg + u];
          h[u] = (_Float16)(t > 0.f ? t : 0.f);
        }
        *(h8_t*)&Bl[n][oc * 8] = h;
      }
    }
    __syncthreads();
#pragma unroll
    for (int ko = 0; ko < 4; ko++) {
      h8_t af = *(const h8_t*)&Wol[wave * 16 + l16][ko * 32 + quad * 8];
#pragma unroll
      for (int t = 0; t < 4; t++) {
        h8_t bf = *(const h8_t*)&Bl[t * 16 + l16][ko * 32 + quad * 8];
        acc[t] = __builtin_amdgcn_mfma_f32_16x16x32_f16(af, bf, acc[t], 0, 0, 0);
      }
    }
  }

#pragma unroll
  for (int r = 0; r < 4; r++) {
    int o = o0 + wave * 16 + quad * 4 + r;
    float ls = 0.f, lq = 0.f;
#pragma unroll
    for (int t = 0; t < 4; t++) {
      float v = acc[t][r];
      ls += v; lq += v * v;
      out2[(size_t)(b * 256 + o) * NTOK + n0 + t * 16 + l16] = (_Float16)v;
    }
    atomicAdd(&ssum[wave * 16 + quad * 4 + r], ls);
    atomicAdd(&ssq[wave * 16 + quad * 4 + r], lq);
  }
  __syncthreads();
  if (tid < 64) {
    atomicAdd(&sum2[o0 + tid], ssum[tid]);
    atomicAdd(&sq2[o0 + tid], ssq[tid]);
  }
}

// ---------------------------------------------------------------------------
// Kernel G: out = relu(sc2*out2 + sh2); BN2 params inline (FROZEN from R9).
// ---------------------------------------------------------------------------
__global__ __launch_bounds__(256) void bn2_kernel(
    const _Float16* __restrict__ out2, const float* __restrict__ sum2,
    const float* __restrict__ sq2, const float* __restrict__ gamma2,
    const float* __restrict__ beta2, float* __restrict__ out)
{
  size_t i = ((size_t)blockIdx.x * 256 + threadIdx.x) * 8;
  int o = (int)((i / NTOK) & 255);
  float m = sum2[o] * (1.f / NSTAT);
  float var = sq2[o] * (1.f / NSTAT) - m * m;
  float s = gamma2[o] * rsqrtf(var + 1e-5f);
  float h = beta2[o] - m * s;
  h8_t v = *(const h8_t*)&out2[i];
  f4_t r0, r1;
#pragma unroll
  for (int u = 0; u < 4; u++) {
    float t0 = s * (float)v[u] + h;
    float t1 = s * (float)v[u + 4] + h;
    r0[u] = t0 > 0.f ? t0 : 0.f;
    r1[u] = t1 > 0.f ? t1 : 0.f;
  }
  *(f4_t*)&out[i] = r0;
  *(f4_t*)&out[i + 4] = r1;
}

// ---------------------------------------------------------------------------
// ws (18.89 MB, known-safe): [0,8K) stats; base: R0..R3 (4.72 MB each):
//   Qt(R0) Kt(R1) V(R2); g1t[n][256] aliases R0+R1 (dead after flash);
//   out2[o][n] aliases R2+R3.  d_out = flash scratch (gcn_acc+l_acc).
// ---------------------------------------------------------------------------
extern "C" void kernel_launch(void* const* d_in, const int* in_sizes, int n_in,
                              void* d_out, int out_size, void* d_ws, size_t ws_size,
                              hipStream_t stream) {
  const float* x      = (const float*)d_in[0];
  const float* Wk     = (const float*)d_in[1];
  const float* Wv     = (const float*)d_in[2];
  const float* Wq     = (const float*)d_in[3];
  const float* Wc1    = (const float*)d_in[4];
  const float* gamma1 = (const float*)d_in[5];
  const float* beta1  = (const float*)d_in[6];
  const float* Wout   = (const float*)d_in[7];
  const float* gamma2 = (const float*)d_in[8];
  const float* beta2  = (const float*)d_in[9];
  float* out = (float*)d_out;

  char* ws = (char*)d_ws;
  float* sum1 = (float*)(ws + 0 * 1024);
  float* sq1  = (float*)(ws + 1 * 1024);
  float* sum2 = (float*)(ws + 2 * 1024);
  float* sq2  = (float*)(ws + 3 * 1024);

  const size_t R = (size_t)NBATCH * NTOK * CMID * 2;  // 4,718,592 B per region
  char* base = ws + 8 * 1024;
  _Float16* Qt   = (_Float16*)(base + 0 * R);
  _Float16* Kt   = (_Float16*)(base + 1 * R);
  _Float16* V    = (_Float16*)(base + 2 * R);
  _Float16* g1t  = (_Float16*)(base + 0 * R);  // [b][n][256], aliases Qt+Kt
  _Float16* out2 = (_Float16*)(base + 2 * R);  // [b][o][n],   aliases V+spare

  float* gcn_acc = (float*)d_out;                              // 9,437,184 B
  float* l_acc   = (float*)((char*)d_out + (size_t)NBATCH * NTOK * CMID * 4);

  hipMemsetAsync(sum1, 0, 4 * 1024, stream);
  hipMemsetAsync(gcn_acc, 0,
                 (size_t)NBATCH * NTOK * CMID * 4 + (size_t)NBATCH * NTOK * 4,
                 stream);

  qkv_kernel<<<dim3(144, 6, 2), 256, 0, stream>>>(x, Wk, Wv, Wq, Qt, Kt, V);
  flash_kernel<<<dim3(72, KCHUNK, 2), 256, 0, stream>>>(Qt, Kt, V, gcn_acc, l_acc);
  conv1_kernel<<<dim3(144, 4, 2), 256, 0, stream>>>(gcn_acc, l_acc, Wc1, g1t, sum1, sq1);
  out_kernel<<<dim3(144, 4, 2), 256, 0, stream>>>(x, g1t, Wout, sum1, sq1, gamma1, beta1,
                                                  out2, sum2, sq2);
  bn2_kernel<<<2304, 256, 0, stream>>>(out2, sum2, sq2, gamma2, beta2, out);
}

// Round 10
// 306.752 us; speedup vs baseline: 1.3999x; 1.0230x over previous
//
#include <hip/hip_runtime.h>

typedef _Float16 h8_t __attribute__((ext_vector_type(8)));
typedef _Float16 h4_t __attribute__((ext_vector_type(4)));
typedef float f4_t __attribute__((ext_vector_type(4)));

#define NTOK 9216
#define CMID 128
#define NBATCH 2
#define KCHUNK 5                  // 720 blocks: all resident at 3 blocks/CU
#define NKT 144                   // 64-key tiles per batch
#define NSTAT 18432.0f            // 2*9216 elements per channel for BN stats

// MFMA fragment recipe (verified R2-R11):
//   A-frag: lane(l16,quad) holds A[m=l16][k=quad*8+j]   (h8 from [m][k] row)
//   B-frag: lane(l16,quad) holds B[n=l16][k=quad*8+j]   (h8 from [n][k] row)
//   D:      lane(l16,quad) holds D[row=quad*4+r][col=l16]
// R8 lesson: W frags must be LDS-staged.
// R6/R10/R11: unified VGPR+AGPR budget; extra live regs across barriers OR
//   complex addressing tips the allocator into scratch.
// R12 (measured): __launch_bounds__(256,4) -> spill. Never below (256,3).
// R13 (measured): swapped QK^T + packed P-store = 186->176 us. Bank
//   conflicts ~1.4e7 are STRUCTURAL (wave64 b128 = 8 dword/bank floor).
// R14 (measured): reg-prefetch of K/V across barriers -> scratch spill.
// R15 (measured): residency ceiling 3 blocks/CU (148 regs/wave unified);
//   grids > 768 blocks run as two dispatch rounds. KCHUNK=5 = best fill.
// R16/R17 (measured): gload_lds into barrier-multiplexed union -> replay
//   race. Abandoned.
// R18 (measured): R13 re-anchor: 331.7 us, flash 173-176.
// R19 (measured): separate Pl grew LDS 36.9->54.3 KB -> HW granted only
//   2 blocks/CU (granularity). 3-block budget is <= ~37 KB/block.
// R20 (measured): T5 setprio around MFMA clusters: flash 176->158.5 us
//   (+10%), MfmaUtil 20.7->23.4, all gates held. Banked.
// R21 (this round): swizzled K-fragment -> P stays IN REGISTERS.
//   QK^T call u reads K rows pi(u,l16) = (l16>>2)*8+(l16&3)+(u&1)*4+
//   (u>>1)*32, so lane(l16,quad) accumulates S for keys quad*8+(u&1)*4+r
//   +(u>>1)*32 == exactly PV's A-frag keys {ch*32+quad*8+j}. pf is a pure
//   per-lane cvt/pack of S -> Pl buffer, its ds_write/ds_read, AND barrier
//   B3 are all deleted (2 barriers/tile). To keep reads conflict-proven,
//   K is stored row-PERMUTED at staging (key k -> LDS row rho(k),
//   rho = ((k&4)<<2)|(k&32)|(((k>>3)&3)<<2)|(k&3)); QK^T then reads the
//   linear Kl[u*16+l16] pattern (bank-identical to R13's). Staging writes
//   stay 4-consecutive-row per wave (rho preserves k&3) -> write pattern
//   bank-identical. LDS 36864->35840 B (no union -> R16 hazard class gone).

__device__ __forceinline__ h8_t cvt_f32x8_h8(const float* p) {
  f4_t a = *(const f4_t*)p, b = *(const f4_t*)(p + 4);
  h8_t h;
#pragma unroll
  for (int u = 0; u < 4; u++) { h[u] = (_Float16)a[u]; h[u + 4] = (_Float16)b[u]; }
  return h;
}

// ---------------------------------------------------------------------------
// Kernel A: QKV projection via MFMA (FROZEN from R9/R13).
// ---------------------------------------------------------------------------
__global__ __launch_bounds__(256) void qkv_kernel(
    const float* __restrict__ x, const float* __restrict__ Wk,
    const float* __restrict__ Wv, const float* __restrict__ Wq,
    _Float16* __restrict__ Qt, _Float16* __restrict__ Kt,
    _Float16* __restrict__ V)
{
  const int b  = blockIdx.z;
  const int n0 = blockIdx.x * 64;
  const int o0 = blockIdx.y * 64;
  const int tid = threadIdx.x;
  const int wave = tid >> 6, lane = tid & 63, quad = lane >> 4, l16 = lane & 15;

  __shared__ _Float16 Wl[64][136];   // A tile [o][c-chunk]
  __shared__ _Float16 xl[64][136];   // B tile [n][c-chunk]; reused as V staging
  __shared__ _Float16 Tt[128][68];   // transpose staging (f16)

  const float* Wsel; int orow;
  if (o0 < 128)      { Wsel = Wq; orow = o0; }
  else if (o0 < 256) { Wsel = Wk; orow = o0 - 128; }
  else               { Wsel = Wv; orow = o0 - 256; }

  f4_t acc[4];
#pragma unroll
  for (int t = 0; t < 4; t++) acc[t] = (f4_t)(0.f);

  for (int kc = 0; kc < 256; kc += 128) {
    __syncthreads();
#pragma unroll
    for (int it = 0; it < 4; it++) {
      int idx = tid + it * 256;
      int row = idx >> 4, oc = idx & 15;
      *(h8_t*)&Wl[row][oc * 8] =
          cvt_f32x8_h8(&Wsel[(size_t)(orow + row) * 256 + kc + oc * 8]);
    }
#pragma unroll
    for (int it = 0; it < 8; it++) {
      int idx = tid + it * 256;
      int cl = idx >> 4, u = idx & 15;
      f4_t v = *(const f4_t*)&x[(size_t)(b * 256 + kc + cl) * NTOK + n0 + u * 4];
      h4_t h;
#pragma unroll
      for (int j = 0; j < 4; j++) h[j] = (_Float16)v[j];
      *(h4_t*)&Tt[cl][u * 4] = h;
    }
    __syncthreads();
#pragma unroll
    for (int it = 0; it < 4; it++) {
      int idx = tid + it * 256;
      int nl = idx & 63, oc = idx >> 6;   // oc 0..15
      h8_t h;
#pragma unroll
      for (int j = 0; j < 8; j++) h[j] = Tt[oc * 8 + j][nl];
      *(h8_t*)&xl[nl][oc * 8] = h;
    }
    __syncthreads();
#pragma unroll
    for (int ko = 0; ko < 4; ko++) {
      h8_t af = *(const h8_t*)&Wl[wave * 16 + l16][ko * 32 + quad * 8];
#pragma unroll
      for (int t = 0; t < 4; t++) {
        h8_t bf = *(const h8_t*)&xl[t * 16 + l16][ko * 32 + quad * 8];
        acc[t] = __builtin_amdgcn_mfma_f32_16x16x32_f16(af, bf, acc[t], 0, 0, 0);
      }
    }
  }

  const float qscale = 0.08838834764831845f * 1.4426950408889634f; // 128^-0.5*log2e
  if (o0 < 256) {
    _Float16* dst = (o0 < 128) ? Qt : Kt;
    const int od = ((o0 < 128) ? o0 : (o0 - 128)) + wave * 16 + quad * 4;
    const float s = (o0 < 128) ? qscale : 1.0f;
#pragma unroll
    for (int t = 0; t < 4; t++) {
      int n = n0 + t * 16 + l16;
      h4_t h;
#pragma unroll
      for (int r = 0; r < 4; r++) h[r] = (_Float16)(acc[t][r] * s);
      *(h4_t*)&dst[(size_t)(b * NTOK + n) * CMID + od] = h;
    }
  } else {
    // V branch: transpose acc through xl (dead after MFMA) -> coalesced h8
    __syncthreads();   // all waves done reading xl
    const int cl0 = wave * 16 + quad * 4;   // local channel row base
#pragma unroll
    for (int t = 0; t < 4; t++)
#pragma unroll
      for (int r = 0; r < 4; r++)
        xl[cl0 + r][t * 16 + l16] = (_Float16)acc[t][r];   // [c][n], pitch 136
    __syncthreads();
    const int c0 = o0 - 256;
#pragma unroll
    for (int it = 0; it < 2; it++) {
      int idx = tid + it * 256;
      int row = idx >> 3, ch = idx & 7;     // row: 64 channels, ch: 8 h8-chunks
      *(h8_t*)&V[(size_t)(b * CMID + c0 + row) * NTOK + n0 + ch * 8] =
          *(const h8_t*)&xl[row][ch * 8];
    }
  }
}

// ---------------------------------------------------------------------------
// Kernel B: split-K flash. R21: swizzled K-fragment, in-register P,
// 2 barriers/tile, no LDS union. + R20 setprio.
// ---------------------------------------------------------------------------
__global__ __launch_bounds__(256, 3) void flash_kernel(
    const _Float16* __restrict__ Qt, const _Float16* __restrict__ Kt,
    const _Float16* __restrict__ V,
    float* __restrict__ gcn_acc, float* __restrict__ l_acc)
{
  const int b  = blockIdx.z;
  const int kc = blockIdx.y;
  const int q0 = blockIdx.x * 128;
  const int tid = threadIdx.x;
  const int wave = tid >> 6, lane = tid & 63, quad = lane >> 4, l16 = lane & 15;

  __shared__ _Float16 Vl[128][72];   // [c][key]            18432 B
  __shared__ _Float16 Kl[64][136];   // [rho(key)][c]       17408 B (no union)

  h8_t qf[2][4];
#pragma unroll
  for (int qi = 0; qi < 2; qi++) {
    const _Float16* qp =
        Qt + (size_t)(b * NTOK + q0 + wave * 32 + qi * 16 + l16) * CMID;
#pragma unroll
    for (int ch = 0; ch < 4; ch++)
      qf[qi][ch] = *(const h8_t*)(qp + ch * 32 + quad * 8);
  }

  f4_t O[2][8];
#pragma unroll
  for (int qi = 0; qi < 2; qi++)
#pragma unroll
    for (int t = 0; t < 8; t++) O[qi][t] = (f4_t)(0.f);
  float l_r[2] = {0.f, 0.f};

  const int t0 = (kc * NKT) / KCHUNK;
  const int t1 = ((kc + 1) * NKT) / KCHUNK;
  for (int k0 = t0 * 64; k0 < t1 * 64; k0 += 64) {
    __syncthreads();   // B1: prior iter's Kl/Vl reads complete
    {
      const h8_t* src = (const h8_t*)(Kt + (size_t)(b * NTOK + k0) * CMID);
#pragma unroll
      for (int r = 0; r < 4; r++) {
        int idx = tid + r * 256;
        int row = idx >> 4, ch = idx & 15;
        // row-permute: key k -> LDS row rho(k); preserves k&3 so the wave's
        // 4-consecutive-row write pattern (bank behavior) is unchanged.
        int pr = ((row & 4) << 2) | (row & 32) | (((row >> 3) & 3) << 2) | (row & 3);
        *(h8_t*)&Kl[pr][ch * 8] = src[idx];
      }
      const _Float16* vs = V + (size_t)(b * CMID) * NTOK + k0;
#pragma unroll
      for (int r = 0; r < 4; r++) {
        int idx = tid + r * 256;
        int row = idx >> 3, ch = idx & 7;
        *(h8_t*)&Vl[row][ch * 8] = *(const h8_t*)(vs + (size_t)row * NTOK + ch * 8);
      }
    }
    __syncthreads();   // B2: tiles staged

    // Swizzled QK^T: call u reads permuted rows u*16+l16 (linear, conflict-
    // proven) which hold key pi(u,l16). Resulting S[qi][u][r] is
    //   query = q0 + wave*32 + qi*16 + l16           (lane-fixed)
    //   key   = k0 + quad*8 + (u&1)*4 + r + (u>>1)*32
    // == PV A-frag keys {ch*32 + quad*8 + j} with ch=u>>1, j=(u&1)*4+r.
    f4_t S[2][4];
#pragma unroll
    for (int qi = 0; qi < 2; qi++)
#pragma unroll
      for (int u = 0; u < 4; u++) S[qi][u] = (f4_t)(0.f);
    __builtin_amdgcn_s_setprio(1);   // T5: favor MFMA-phase waves
#pragma unroll
    for (int ck = 0; ck < 4; ck++)
#pragma unroll
      for (int u = 0; u < 4; u++) {
        h8_t kf = *(const h8_t*)&Kl[u * 16 + l16][ck * 32 + quad * 8];
        S[0][u] = __builtin_amdgcn_mfma_f32_16x16x32_f16(kf, qf[0][ck], S[0][u], 0, 0, 0);
        S[1][u] = __builtin_amdgcn_mfma_f32_16x16x32_f16(kf, qf[1][ck], S[1][u], 0, 0, 0);
      }
    __builtin_amdgcn_s_setprio(0);

    // exp + pack entirely in registers: pf[qi][ch][j] = P[query][ch*32+quad*8+j]
    h8_t pf[2][2];
#pragma unroll
    for (int qi = 0; qi < 2; qi++)
#pragma unroll
      for (int u = 0; u < 4; u++)
#pragma unroll
        for (int r = 0; r < 4; r++) {
          float p = exp2f(S[qi][u][r] - 8.0f);
          l_r[qi] += p;
          pf[qi][u >> 1][(u & 1) * 4 + r] = (_Float16)p;
        }

    __builtin_amdgcn_s_setprio(1);   // T5: PV MFMA cluster
#pragma unroll
    for (int ch = 0; ch < 2; ch++)
#pragma unroll
      for (int t = 0; t < 8; t++) {
        h8_t vf = *(const h8_t*)&Vl[t * 16 + l16][ch * 32 + quad * 8];
        O[0][t] = __builtin_amdgcn_mfma_f32_16x16x32_f16(pf[0][ch], vf, O[0][t], 0, 0, 0);
        O[1][t] = __builtin_amdgcn_mfma_f32_16x16x32_f16(pf[1][ch], vf, O[1][t], 0, 0, 0);
      }
    __builtin_amdgcn_s_setprio(0);
  }

  // l-reduce: lane's partials cover keys {quad*8+j, 32+quad*8+j}; union over
  // quads = all 64 keys once. Sum across quads (lane bits 4,5), one atomic
  // per query from quad 0.
#pragma unroll
  for (int qi = 0; qi < 2; qi++) {
    float v = l_r[qi];
    v += __shfl_xor(v, 16);
    v += __shfl_xor(v, 32);
    if (quad == 0)
      atomicAdd(&l_acc[b * NTOK + q0 + wave * 32 + qi * 16 + l16], v);
  }
#pragma unroll
  for (int qi = 0; qi < 2; qi++)
#pragma unroll
    for (int t = 0; t < 8; t++)
#pragma unroll
      for (int r = 0; r < 4; r++)
        atomicAdd(&gcn_acc[(size_t)(b * NTOK + q0 + wave * 32 + qi * 16 + quad * 4 + r)
                               * CMID + t * 16 + l16],
                  O[qi][t][r]);
}

// ---------------------------------------------------------------------------
// Kernel C: conv1 via MFMA (FROZEN from R9).
// ---------------------------------------------------------------------------
__global__ __launch_bounds__(256) void conv1_kernel(
    const float* __restrict__ gcn_acc, const float* __restrict__ l_acc,
    const float* __restrict__ Wc1,
    _Float16* __restrict__ g1t, float* __restrict__ sum1, float* __restrict__ sq1)
{
  const int b  = blockIdx.z;
  const int n0 = blockIdx.x * 64;
  const int o0 = blockIdx.y * 64;
  const int tid = threadIdx.x;
  const int wave = tid >> 6, lane = tid & 63, quad = lane >> 4, l16 = lane & 15;

  __shared__ _Float16 Gl[64][136];   // [n][c]
  __shared__ _Float16 Wcl[64][136];  // [o][c]
  __shared__ float rl[64];
  __shared__ float ssum[64], ssq[64];

  if (tid < 64) {
    rl[tid] = 1.0f / l_acc[b * NTOK + n0 + tid];
    ssum[tid] = 0.f; ssq[tid] = 0.f;
  }
  __syncthreads();

#pragma unroll
  for (int it = 0; it < 4; it++) {
    int idx = tid + it * 256;
    int n = idx >> 4, oc = idx & 15;
    const float* gp = &gcn_acc[(size_t)(b * NTOK + n0 + n) * CMID + oc * 8];
    float s = rl[n];
    f4_t a = *(const f4_t*)gp, c = *(const f4_t*)(gp + 4);
    h8_t h;
#pragma unroll
    for (int u = 0; u < 4; u++) {
      h[u] = (_Float16)(a[u] * s);
      h[u + 4] = (_Float16)(c[u] * s);
    }
    *(h8_t*)&Gl[n][oc * 8] = h;
  }
#pragma unroll
  for (int it = 0; it < 4; it++) {
    int idx = tid + it * 256;
    int row = idx >> 4, oc = idx & 15;
    *(h8_t*)&Wcl[row][oc * 8] =
        cvt_f32x8_h8(&Wc1[(size_t)(o0 + row) * 128 + oc * 8]);
  }
  __syncthreads();

  f4_t acc[4];
#pragma unroll
  for (int t = 0; t < 4; t++) acc[t] = (f4_t)(0.f);
#pragma unroll
  for (int ko = 0; ko < 4; ko++) {
    h8_t af = *(const h8_t*)&Gl[wave * 16 + l16][ko * 32 + quad * 8];
#pragma unroll
    for (int t = 0; t < 4; t++) {
      h8_t bf = *(const h8_t*)&Wcl[t * 16 + l16][ko * 32 + quad * 8];
      acc[t] = __builtin_amdgcn_mfma_f32_16x16x32_f16(af, bf, acc[t], 0, 0, 0);
    }
  }

  // D: row = n (wave*16+quad*4+r), col = o (t*16+l16)
#pragma unroll
  for (int t = 0; t < 4; t++) {
    int ol = t * 16 + l16;
    float ls = 0.f, lq = 0.f;
#pragma unroll
    for (int r = 0; r < 4; r++) {
      float v = acc[t][r];
      ls += v; lq += v * v;
      g1t[(size_t)(b * NTOK + n0 + wave * 16 + quad * 4 + r) * 256 + o0 + ol] =
          (_Float16)v;
    }
    atomicAdd(&ssum[ol], ls);
    atomicAdd(&ssq[ol], lq);
  }
  __syncthreads();
  if (tid < 64) {
    atomicAdd(&sum1[o0 + tid], ssum[tid]);
    atomicAdd(&sq1[o0 + tid], ssq[tid]);
  }
}

// ---------------------------------------------------------------------------
// Kernel E: out2 via MFMA (FROZEN from R9).
// ---------------------------------------------------------------------------
__global__ __launch_bounds__(256) void out_kernel(
    const float* __restrict__ x, const _Float16* __restrict__ g1t,
    const float* __restrict__ Wout,
    const float* __restrict__ sum1, const float* __restrict__ sq1,
    const float* __restrict__ gamma1, const float* __restrict__ beta1,
    _Float16* __restrict__ out2, float* __restrict__ sum2, float* __restrict__ sq2)
{
  const int b  = blockIdx.z;
  const int n0 = blockIdx.x * 64;
  const int o0 = blockIdx.y * 64;
  const int tid = threadIdx.x;
  const int wave = tid >> 6, lane = tid & 63, quad = lane >> 4, l16 = lane & 15;

  __shared__ _Float16 Wol[64][136];  // A tile [o][k-chunk]
  __shared__ _Float16 Bl[64][136];   // B tile [n][k-chunk]
  __shared__ _Float16 Tt[128][68];   // transpose staging (f16)
  __shared__ _Float16 scs[256], shs[256];
  __shared__ float ssum[64], ssq[64];

  {  // BN1 params inline
    float m = sum1[tid] * (1.f / NSTAT);
    float var = sq1[tid] * (1.f / NSTAT) - m * m;
    float s = gamma1[tid] * rsqrtf(var + 1e-5f);
    scs[tid] = (_Float16)s;
    shs[tid] = (_Float16)(beta1[tid] - m * s);
  }
  if (tid < 64) { ssum[tid] = 0.f; ssq[tid] = 0.f; }

  f4_t acc[4];
#pragma unroll
  for (int t = 0; t < 4; t++) acc[t] = (f4_t)(0.f);

  for (int kc = 0; kc < 512; kc += 128) {
    __syncthreads();
#pragma unroll
    for (int it = 0; it < 4; it++) {
      int idx = tid + it * 256;
      int row = idx >> 4, oc = idx & 15;
      *(h8_t*)&Wol[row][oc * 8] =
          cvt_f32x8_h8(&Wout[(size_t)(o0 + row) * 512 + kc + oc * 8]);
    }
    if (kc < 256) {
#pragma unroll
      for (int it = 0; it < 8; it++) {
        int idx = tid + it * 256;
        int cl = idx >> 4, u = idx & 15;
        f4_t v = *(const f4_t*)&x[(size_t)(b * 256 + kc + cl) * NTOK + n0 + u * 4];
        h4_t h;
#pragma unroll
        for (int j = 0; j < 4; j++) h[j] = (_Float16)v[j];
        *(h4_t*)&Tt[cl][u * 4] = h;
      }
      __syncthreads();
#pragma unroll
      for (int it = 0; it < 4; it++) {
        int idx = tid + it * 256;
        int nl = idx & 63, oc = idx >> 6;
        h8_t h;
#pragma unroll
        for (int j = 0; j < 8; j++) h[j] = Tt[oc * 8 + j][nl];
        *(h8_t*)&Bl[nl][oc * 8] = h;
      }
    } else {
#pragma unroll
      for (int it = 0; it < 4; it++) {
        int idx = tid + it * 256;
        int n = idx >> 4, oc = idx & 15;
        int cg = kc - 256 + oc * 8;
        h8_t g = *(const h8_t*)&g1t[(size_t)(b * NTOK + n0 + n) * 256 + cg];
        h8_t h;
#pragma unroll
        for (int u = 0; u < 8; u++) {
          float t = (float)scs[cg + u] * (float)g[u] + (float)shs[cg + u];
          h[u] = (_Float16)(t > 0.f ? t : 0.f);
        }
        *(h8_t*)&Bl[n][oc * 8] = h;
      }
    }
    __syncthreads();
#pragma unroll
    for (int ko = 0; ko < 4; ko++) {
      h8_t af = *(const h8_t*)&Wol[wave * 16 + l16][ko * 32 + quad * 8];
#pragma unroll
      for (int t = 0; t < 4; t++) {
        h8_t bf = *(const h8_t*)&Bl[t * 16 + l16][ko * 32 + quad * 8];
        acc[t] = __builtin_amdgcn_mfma_f32_16x16x32_f16(af, bf, acc[t], 0, 0, 0);
      }
    }
  }

#pragma unroll
  for (int r = 0; r < 4; r++) {
    int o = o0 + wave * 16 + quad * 4 + r;
    float ls = 0.f, lq = 0.f;
#pragma unroll
    for (int t = 0; t < 4; t++) {
      float v = acc[t][r];
      ls += v; lq += v * v;
      out2[(size_t)(b * 256 + o) * NTOK + n0 + t * 16 + l16] = (_Float16)v;
    }
    atomicAdd(&ssum[wave * 16 + quad * 4 + r], ls);
    atomicAdd(&ssq[wave * 16 + quad * 4 + r], lq);
  }
  __syncthreads();
  if (tid < 64) {
    atomicAdd(&sum2[o0 + tid], ssum[tid]);
    atomicAdd(&sq2[o0 + tid], ssq[tid]);
  }
}

// ---------------------------------------------------------------------------
// Kernel G: out = relu(sc2*out2 + sh2); BN2 params inline (FROZEN from R9).
// ---------------------------------------------------------------------------
__global__ __launch_bounds__(256) void bn2_kernel(
    const _Float16* __restrict__ out2, const float* __restrict__ sum2,
    const float* __restrict__ sq2, const float* __restrict__ gamma2,
    const float* __restrict__ beta2, float* __restrict__ out)
{
  size_t i = ((size_t)blockIdx.x * 256 + threadIdx.x) * 8;
  int o = (int)((i / NTOK) & 255);
  float m = sum2[o] * (1.f / NSTAT);
  float var = sq2[o] * (1.f / NSTAT) - m * m;
  float s = gamma2[o] * rsqrtf(var + 1e-5f);
  float h = beta2[o] - m * s;
  h8_t v = *(const h8_t*)&out2[i];
  f4_t r0, r1;
#pragma unroll
  for (int u = 0; u < 4; u++) {
    float t0 = s * (float)v[u] + h;
    float t1 = s * (float)v[u + 4] + h;
    r0[u] = t0 > 0.f ? t0 : 0.f;
    r1[u] = t1 > 0.f ? t1 : 0.f;
  }
  *(f4_t*)&out[i] = r0;
  *(f4_t*)&out[i + 4] = r1;
}

// ---------------------------------------------------------------------------
// ws (18.89 MB, known-safe): [0,8K) stats; base: R0..R3 (4.72 MB each):
//   Qt(R0) Kt(R1) V(R2); g1t[n][256] aliases R0+R1 (dead after flash);
//   out2[o][n] aliases R2+R3.  d_out = flash scratch (gcn_acc+l_acc).
// ---------------------------------------------------------------------------
extern "C" void kernel_launch(void* const* d_in, const int* in_sizes, int n_in,
                              void* d_out, int out_size, void* d_ws, size_t ws_size,
                              hipStream_t stream) {
  const float* x      = (const float*)d_in[0];
  const float* Wk     = (const float*)d_in[1];
  const float* Wv     = (const float*)d_in[2];
  const float* Wq     = (const float*)d_in[3];
  const float* Wc1    = (const float*)d_in[4];
  const float* gamma1 = (const float*)d_in[5];
  const float* beta1  = (const float*)d_in[6];
  const float* Wout   = (const float*)d_in[7];
  const float* gamma2 = (const float*)d_in[8];
  const float* beta2  = (const float*)d_in[9];
  float* out = (float*)d_out;

  char* ws = (char*)d_ws;
  float* sum1 = (float*)(ws + 0 * 1024);
  float* sq1  = (float*)(ws + 1 * 1024);
  float* sum2 = (float*)(ws + 2 * 1024);
  float* sq2  = (float*)(ws + 3 * 1024);

  const size_t R = (size_t)NBATCH * NTOK * CMID * 2;  // 4,718,592 B per region
  char* base = ws + 8 * 1024;
  _Float16* Qt   = (_Float16*)(base + 0 * R);
  _Float16* Kt   = (_Float16*)(base + 1 * R);
  _Float16* V    = (_Float16*)(base + 2 * R);
  _Float16* g1t  = (_Float16*)(base + 0 * R);  // [b][n][256], aliases Qt+Kt
  _Float16* out2 = (_Float16*)(base + 2 * R);  // [b][o][n],   aliases V+spare

  float* gcn_acc = (float*)d_out;                              // 9,437,184 B
  float* l_acc   = (float*)((char*)d_out + (size_t)NBATCH * NTOK * CMID * 4);

  hipMemsetAsync(sum1, 0, 4 * 1024, stream);
  hipMemsetAsync(gcn_acc, 0,
                 (size_t)NBATCH * NTOK * CMID * 4 + (size_t)NBATCH * NTOK * 4,
                 stream);

  qkv_kernel<<<dim3(144, 6, 2), 256, 0, stream>>>(x, Wk, Wv, Wq, Qt, Kt, V);
  flash_kernel<<<dim3(72, KCHUNK, 2), 256, 0, stream>>>(Qt, Kt, V, gcn_acc, l_acc);
  conv1_kernel<<<dim3(144, 4, 2), 256, 0, stream>>>(gcn_acc, l_acc, Wc1, g1t, sum1, sq1);
  out_kernel<<<dim3(144, 4, 2), 256, 0, stream>>>(x, g1t, Wout, sum1, sq1, gamma1, beta1,
                                                  out2, sum2, sq2);
  bn2_kernel<<<2304, 256, 0, stream>>>(out2, sum2, sq2, gamma2, beta2, out);
}